// Round 14
// baseline (67.357 us; speedup 1.0000x reference)
//
#include <hip/hip_runtime.h>

// Problem constants
#define B_    4
#define A_    66000
#define NA_   (B_ * A_)          // 264000 anchors
#define N_    30
#define T_    5
#define NLT   5
#define CSUM  277
#define CTOT  278                // 1 + 277 logits per anchor
#define ROWS  31                 // N+1 table rows per batch
#define NROWS (B_ * ROWS)        // 124
#define WPR   11                 // odd row stride (>=10 so w1 read stays in-row)
#define NBW   (NROWS * WPR)      // 1364 words = 5456 B LDS
#define NE    (NA_ * CTOT)       // 73,392,000 elements
#define NE32  (NE / 32)          // 2,293,500 32-packs (exact)

#define BLK       256
#define GRID_CLS  1792           // 7 blocks/CU; NE32/(1792*256)=5.0005 -> balanced

typedef float fx4 __attribute__((ext_vector_type(4)));
typedef float fx2 __attribute__((ext_vector_type(2)));

// ---------------- helpers ----------------

// Pair focal as float2 math (invites v_pk_*_f32).
// b2 = 2 label bits; c25/c75 = mask*0.25 / mask*0.75 for this pair.
__device__ __forceinline__ fx2 pair_focal(float x0, float x1, unsigned b2,
                                          float c25, float c75, fx2 acc) {
    bool y0 = (b2 & 1u) != 0u, y1 = (b2 & 2u) != 0u;
    float s0 = y0 ? -x0 : x0,  s1 = y1 ? -x1 : x1;
    float k0 = y0 ? c25 : c75, k1 = y1 ? c25 : c75;
    // t = exp(-|s|) = exp2(-|x|*log2e)   (|s| == |x|)
    float t0 = __builtin_amdgcn_exp2f(-fabsf(x0) * 1.4426950408889634f);
    float t1 = __builtin_amdgcn_exp2f(-fabsf(x1) * 1.4426950408889634f);
    fx2 t = {t0, t1};
    fx2 u = t + 1.0f;
    fx2 L = { __builtin_amdgcn_logf(u.x), __builtin_amdgcn_logf(u.y) }; // log2(1+t)
    fx2 sp = { fmaxf(s0, 0.f), fmaxf(s1, 0.f) };
    sp += L * 0.6931471805599453f;                 // softplus(s)
    fx2 inv = { __builtin_amdgcn_rcpf(u.x), __builtin_amdgcn_rcpf(u.y) };
    fx2 ti = t * inv;
    fx2 sig = { s0 >= 0.f ? inv.x : ti.x, s1 >= 0.f ? inv.y : ti.y };   // sigmoid(s)
    fx2 term = { k0, k1 };
    term *= sp;
    return acc + term * (sig * sig);
}

__device__ __forceinline__ float sl1(float d) {
    float ad = fabsf(d);
    return (ad < (1.f / 9.f)) ? 4.5f * ad * ad : ad - (1.f / 18.f);
}

__device__ __forceinline__ float block_reduce(float v, float* sdata) {
    #pragma unroll
    for (int off = 32; off > 0; off >>= 1) v += __shfl_down(v, off, 64);
    int lane = threadIdx.x & 63, wid = threadIdx.x >> 6;
    if (lane == 0) sdata[wid] = v;
    __syncthreads();
    int nw = blockDim.x >> 6;
    if (wid == 0) {
        v = (lane < nw) ? sdata[lane] : 0.f;
        #pragma unroll
        for (int off = 32; off > 0; off >>= 1) v += __shfl_down(v, off, 64);
    }
    return v;
}

// ---------------- kernels ----------------

// Self-contained main kernel (see R13): per-block LDS label table from gtl,
// fused reg/pos pass, then 128 B (32 elements) per lane-iteration focal sweep
// with branch-free boundary handling and inline rowid from lbin.
// No cross-block fences/atomics (R10/R11: ~220us serialized tail on 8 XCDs).
__global__ __launch_bounds__(BLK) void cls_kernel(
    const fx4* __restrict__ conf4, const int* __restrict__ lbin,
    const int* __restrict__ gtl,
    const float* __restrict__ pred, const float* __restrict__ gt,
    float* __restrict__ cls_part, float* __restrict__ reg_part,
    float* __restrict__ pos_part)
{
    __shared__ unsigned lbits[NBW];
    for (int i = threadIdx.x; i < NBW; i += BLK) lbits[i] = 0u;
    __syncthreads();
    for (int r = threadIdx.x; r < NROWS; r += BLK)
        if ((r % ROWS) != 0) atomicOr(&lbits[r * WPR], 1u);     // pos bit, col 0
    for (int idx = threadIdx.x; idx < B_ * N_ * NLT; idx += BLK) {
        int lt = idx % NLT;
        int bn = idx / NLT;
        int n  = bn % N_;
        int b  = bn / N_;
        const int nc_arr[NLT]  = {10, 23, 69, 163, 12};
        const int off_arr[NLT] = {0, 10, 33, 102, 265};
        int nc  = nc_arr[lt];
        int off = off_arr[lt] + 1;              // +1: col 0 is pos
        const int* g = gtl + (size_t)(((b * N_ + n) * NLT + lt)) * T_;
        int row = b * ROWS + (n + 1);
        bool valid = true;
        #pragma unroll
        for (int t = 0; t < T_; ++t) {
            int v = g[t];
            valid = valid && (v >= 0);
            if (valid) {
                int c = off + ((v < nc) ? v : (nc - 1));
                atomicOr(&lbits[row * WPR + (c >> 5)], 1u << (c & 31));
            }
        }
    }
    __syncthreads();

    // ---- regression loss + pos count: one anchor per thread (grid > NA_)
    float racc = 0.f, pacc = 0.f;
    {
        unsigned i = blockIdx.x * BLK + threadIdx.x;
        if (i < NA_) {
            int lb = lbin[i];
            if (lb > 0) {
                pacc = 1.f;
                float4 pv = *(const float4*)(pred + (size_t)4 * i);
                float4 gv = *(const float4*)(gt + (size_t)4 * i);
                racc = sl1(pv.x - gv.x) + sl1(pv.y - gv.y)
                     + sl1(pv.z - gv.z) + sl1(pv.w - gv.w);
            }
        }
    }

    // ---- focal sweep: 128 B (32 elements) per lane-iteration, branch-free
    fx2 acc2 = {0.f, 0.f};
    unsigned stride = gridDim.x * BLK;
    for (unsigned i = blockIdx.x * BLK + threadIdx.x; i < NE32; i += stride) {
        fx4 x0 = conf4[8u * i];          // elements 32i..32i+3
        fx4 x1 = conf4[8u * i + 1u];
        fx4 x2 = conf4[8u * i + 2u];
        fx4 x3 = conf4[8u * i + 3u];
        fx4 x4 = conf4[8u * i + 4u];
        fx4 x5 = conf4[8u * i + 5u];
        fx4 x6 = conf4[8u * i + 6u];
        fx4 x7 = conf4[8u * i + 7u];
        unsigned i32 = i * 32u;
        unsigned a  = i32 / CTOT;        // magic-mul div
        unsigned c0 = i32 - a * CTOT;    // even, 0..276
        // inline rowid from lbin
        unsigned bA = a / A_;            // magic-mul div
        unsigned rA = a - bA * A_;
        unsigned bB = bA + ((rA + 1u == A_) ? 1u : 0u);
        int lbA = lbin[a];
        int lbB = lbin[(a + 1u < NA_) ? (a + 1u) : (NA_ - 1u)]; // clamped; dead
                                         // when a is the last anchor (no cross)
        bool okA = lbA >= 0, okB = lbB >= 0;
        unsigned duA = (lbA > 0) ? (unsigned)lbA : 0u;
        unsigned duB = (lbB > 0) ? (unsigned)lbB : 0u;
        unsigned bwA = okA ? (bA * ROWS + duA) * WPR : 0u;
        unsigned bwB = okB ? (bB * ROWS + duB) * WPR : 0u;
        float mA = okA ? 1.f : 0.f;
        float mB = okB ? 1.f : 0.f;
        float c25A = 0.25f * mA, c75A = 0.75f * mA;
        float c25B = 0.25f * mB, c75B = 0.75f * mB;
        unsigned wi = c0 >> 5, sh = c0 & 31u;     // wi <= 8
        unsigned w0  = lbits[bwA + wi];
        unsigned w1  = lbits[bwA + wi + 1u];      // WPR=11 keeps this in-row
        unsigned wB0 = lbits[bwB];
        // 32-bit window of row-A labels at c0: ww bits sh..sh+31, sh+31<=62 ok
        unsigned wfull = (unsigned)((((unsigned long long)w1 << 32) | w0) >> sh);
        unsigned bnd  = CTOT - c0;                // elements k < bnd belong to A
        bool cross    = bnd < 32u;                // c0 >= 248; bnd in {2..30}, even
        unsigned w32  = cross ? ((wfull & ((1u << bnd) - 1u)) | (wB0 << bnd))
                              : wfull;
        // bnd even -> pairs never straddle; pair k (elems 2k,2k+1) uses B iff 2k>=bnd
        #define PSEL(k) ((cross && bnd <= (2u*(k))) )
        #define Q(k) float q25_##k = PSEL(k) ? c25B : c25A, q75_##k = PSEL(k) ? c75B : c75A
        Q(1); Q(2); Q(3); Q(4); Q(5); Q(6); Q(7); Q(8);
        Q(9); Q(10); Q(11); Q(12); Q(13); Q(14); Q(15);
        #undef Q
        #undef PSEL
        acc2 = pair_focal(x0.x, x0.y,  w32 & 3u,         c25A,  c75A,  acc2);
        acc2 = pair_focal(x0.z, x0.w, (w32 >>  2) & 3u,  q25_1, q75_1, acc2);
        acc2 = pair_focal(x1.x, x1.y, (w32 >>  4) & 3u,  q25_2, q75_2, acc2);
        acc2 = pair_focal(x1.z, x1.w, (w32 >>  6) & 3u,  q25_3, q75_3, acc2);
        acc2 = pair_focal(x2.x, x2.y, (w32 >>  8) & 3u,  q25_4, q75_4, acc2);
        acc2 = pair_focal(x2.z, x2.w, (w32 >> 10) & 3u,  q25_5, q75_5, acc2);
        acc2 = pair_focal(x3.x, x3.y, (w32 >> 12) & 3u,  q25_6, q75_6, acc2);
        acc2 = pair_focal(x3.z, x3.w, (w32 >> 14) & 3u,  q25_7, q75_7, acc2);
        acc2 = pair_focal(x4.x, x4.y, (w32 >> 16) & 3u,  q25_8, q75_8, acc2);
        acc2 = pair_focal(x4.z, x4.w, (w32 >> 18) & 3u,  q25_9, q75_9, acc2);
        acc2 = pair_focal(x5.x, x5.y, (w32 >> 20) & 3u,  q25_10, q75_10, acc2);
        acc2 = pair_focal(x5.z, x5.w, (w32 >> 22) & 3u,  q25_11, q75_11, acc2);
        acc2 = pair_focal(x6.x, x6.y, (w32 >> 24) & 3u,  q25_12, q75_12, acc2);
        acc2 = pair_focal(x6.z, x6.w, (w32 >> 26) & 3u,  q25_13, q75_13, acc2);
        acc2 = pair_focal(x7.x, x7.y, (w32 >> 28) & 3u,  q25_14, q75_14, acc2);
        acc2 = pair_focal(x7.z, x7.w, (w32 >> 30) & 3u,  q25_15, q75_15, acc2);
    }

    __shared__ float sdata[BLK / 64];
    float rc = block_reduce(acc2.x + acc2.y, sdata);
    __syncthreads();
    float rr = block_reduce(racc, sdata);
    __syncthreads();
    float rp = block_reduce(pacc, sdata);
    if (threadIdx.x == 0) {
        cls_part[blockIdx.x] = rc;
        reg_part[blockIdx.x] = rr;
        pos_part[blockIdx.x] = rp;
    }
}

// Deterministic final reduction + normalization (tiny stream-ordered kernel).
__global__ void finalize_kernel(
    const float* __restrict__ cls_part, const float* __restrict__ reg_part,
    const float* __restrict__ pos_part, float* __restrict__ out)
{
    __shared__ float sdata[256 / 64];
    float c = 0.f, r = 0.f, pz = 0.f;
    for (int i = threadIdx.x; i < GRID_CLS; i += blockDim.x) {
        c  += cls_part[i];
        r  += reg_part[i];
        pz += pos_part[i];
    }
    c = block_reduce(c, sdata);
    __syncthreads();
    r = block_reduce(r, sdata);
    __syncthreads();
    pz = block_reduce(pz, sdata);
    if (threadIdx.x == 0) {
        float np = fmaxf(1.f, pz);
        out[0] = r / (np * 4.f);   // regression_loss
        out[1] = c / np;           // cls_loss
    }
}

// ---------------- launch ----------------

extern "C" void kernel_launch(void* const* d_in, const int* in_sizes, int n_in,
                              void* d_out, int out_size, void* d_ws, size_t ws_size,
                              hipStream_t stream) {
    const float* conf = (const float*)d_in[0];
    const float* pred = (const float*)d_in[1];
    const float* gt   = (const float*)d_in[2];
    const int*   gtl  = (const int*)d_in[3];
    const int*   lbin = (const int*)d_in[4];
    float* out = (float*)d_out;

    float* cls_part = (float*)d_ws;
    float* reg_part = cls_part + GRID_CLS;
    float* pos_part = reg_part + GRID_CLS;

    hipLaunchKernelGGL(cls_kernel, dim3(GRID_CLS), dim3(BLK), 0, stream,
                       (const fx4*)conf, lbin, gtl, pred, gt,
                       cls_part, reg_part, pos_part);
    hipLaunchKernelGGL(finalize_kernel, dim3(1), dim3(256), 0, stream,
                       cls_part, reg_part, pos_part, out);
}